// Round 7
// baseline (2209.524 us; speedup 1.0000x reference)
//
#include <hip/hip_runtime.h>
#include <math.h>

// XFADS: N=32, T=1024, D_OBS=128, D_Z=64, D_U=8, H_ENC=256, H_BW=128, H_DYN=256, D_A=128
#define T_LEN 1024
#define NB 32

typedef _Float16 h2 __attribute__((ext_vector_type(2)));

__device__ __forceinline__ h2 f2h2(float f) { return __builtin_bit_cast(h2, f); }

__device__ __forceinline__ float dot2(h2 a, h2 b, float c) {
#if __has_builtin(__builtin_amdgcn_fdot2)
    return __builtin_amdgcn_fdot2(a, b, c, false);
#else
    return fmaf((float)a[0], (float)b[0], fmaf((float)a[1], (float)b[1], c));
#endif
}

__device__ __forceinline__ float softplus_f(float x) {
    return fmaxf(x, 0.f) + log1pf(expf(-fabsf(x)));
}

__device__ __forceinline__ float fast_tanh(float x) {
    float e = __builtin_amdgcn_exp2f(x * 2.88539008177792681472f);
    float r = __builtin_amdgcn_rcpf(1.f + e);
    return 1.f - 2.f * r;
}

// -------------------------------------------------------------------------
// K1: encoder  h = tanh(y@W1+b1); a = h@W2+b2;
//     apre[t][n][:] = a@bw_wa + bw_b
//     preU[t][n][:] = u@dyn_w1[64:72] + dyn_b1
// -------------------------------------------------------------------------
__global__ __launch_bounds__(256) void k_encoder(
    const float* __restrict__ y, const float* __restrict__ u,
    const float* __restrict__ w1, const float* __restrict__ b1,
    const float* __restrict__ w2, const float* __restrict__ b2,
    const float* __restrict__ wa, const float* __restrict__ bb,
    const float* __restrict__ dynw1, const float* __restrict__ dynb1,
    float* __restrict__ apre, float* __restrict__ preU)
{
    __shared__ float ly[8][128];
    __shared__ float lh[8][256];
    __shared__ float la[8][128];
    __shared__ float lu[8][8];
    const int tid = threadIdx.x;
    const int row0 = blockIdx.x * 8;

    ((float4*)&ly[0][0])[tid] = ((const float4*)(y + (size_t)row0 * 128))[tid];
    if (tid < 16)
        ((float4*)&lu[0][0])[tid] = ((const float4*)(u + (size_t)row0 * 8))[tid];
    __syncthreads();

    {
        float acc[8] = {0,0,0,0,0,0,0,0};
        for (int i = 0; i < 128; i += 4) {
            float w0 = w1[(i+0)*256 + tid];
            float w1v = w1[(i+1)*256 + tid];
            float w2v = w1[(i+2)*256 + tid];
            float w3 = w1[(i+3)*256 + tid];
            #pragma unroll
            for (int r = 0; r < 8; ++r) {
                float4 yv = *(const float4*)&ly[r][i];
                acc[r] += yv.x*w0 + yv.y*w1v + yv.z*w2v + yv.w*w3;
            }
        }
        float bias = b1[tid];
        #pragma unroll
        for (int r = 0; r < 8; ++r) lh[r][tid] = fast_tanh(acc[r] + bias);
    }
    __syncthreads();

    {
        const int d = tid & 127, rh = tid >> 7;
        float acc[4] = {0,0,0,0};
        for (int i = 0; i < 256; i += 4) {
            float w0 = w2[(i+0)*128 + d];
            float w1v = w2[(i+1)*128 + d];
            float w2v = w2[(i+2)*128 + d];
            float w3 = w2[(i+3)*128 + d];
            #pragma unroll
            for (int q = 0; q < 4; ++q) {
                float4 hv = *(const float4*)&lh[rh*4+q][i];
                acc[q] += hv.x*w0 + hv.y*w1v + hv.z*w2v + hv.w*w3;
            }
        }
        float bias = b2[d];
        #pragma unroll
        for (int q = 0; q < 4; ++q) la[rh*4+q][d] = acc[q] + bias;
    }
    __syncthreads();

    {
        const int j = tid & 127, rh = tid >> 7;
        float acc[4] = {0,0,0,0};
        for (int i = 0; i < 128; i += 4) {
            float w0 = wa[(i+0)*128 + j];
            float w1v = wa[(i+1)*128 + j];
            float w2v = wa[(i+2)*128 + j];
            float w3 = wa[(i+3)*128 + j];
            #pragma unroll
            for (int q = 0; q < 4; ++q) {
                float4 av = *(const float4*)&la[rh*4+q][i];
                acc[q] += av.x*w0 + av.y*w1v + av.z*w2v + av.w*w3;
            }
        }
        float bias = bb[j];
        #pragma unroll
        for (int q = 0; q < 4; ++q) {
            int rn = row0 + rh*4 + q;
            int n = rn >> 10, t = rn & 1023;
            apre[((size_t)t*NB + n)*128 + j] = acc[q] + bias;
        }
    }

    {
        float wu[8];
        #pragma unroll
        for (int c = 0; c < 8; ++c) wu[c] = dynw1[(64 + c)*256 + tid];
        float bias = dynb1[tid];
        #pragma unroll
        for (int r = 0; r < 8; ++r) {
            float acc = bias;
            #pragma unroll
            for (int c = 0; c < 8; ++c) acc += lu[r][c] * wu[c];
            int rn = row0 + r;
            int n = rn >> 10, t = rn & 1023;
            preU[((size_t)t*NB + n)*256 + tid] = acc;
        }
    }
}

// -------------------------------------------------------------------------
// K2: backward RNN scan — SINGLE WAVE per batch, zero barriers/shuffles.
// Lane l owns output columns j = l and l+64. WhT[j][i] (f16) in LDS,
// XOR-swizzled 16B chunks (chunk' = chunk ^ (j&15)) -> b128 row reads are
// bank-optimal. State h[128] f16 in LDS: per-lane b16 writes, broadcast
// b128 chunk reads. hcell_t = tanh(apre_t + Wh h_{t+1}).
// -------------------------------------------------------------------------
__global__ __launch_bounds__(64, 1) void k_bwscan(
    const float* __restrict__ apre, const float* __restrict__ wh,
    float* __restrict__ hcell)
{
    const int n = blockIdx.x;
    const int l = threadIdx.x;
    __shared__ __align__(16) _Float16 wht[128 * 128];  // 32 KB, row j: 16 chunks
    __shared__ __align__(16) _Float16 hbuf[128];

    // setup: WhT[j][i] = wh[i*128 + j], chunk-swizzled
    for (int e = l; e < 128 * 16; e += 64) {       // (j, c) chunk tasks
        int j = e & 127, c = e >> 7;
        const float* s = wh + (size_t)(c * 8) * 128 + j;
        h2 p0 = h2{(_Float16)s[0*128], (_Float16)s[1*128]};
        h2 p1 = h2{(_Float16)s[2*128], (_Float16)s[3*128]};
        h2 p2 = h2{(_Float16)s[4*128], (_Float16)s[5*128]};
        h2 p3 = h2{(_Float16)s[6*128], (_Float16)s[7*128]};
        float4 pk = make_float4(__builtin_bit_cast(float, p0), __builtin_bit_cast(float, p1),
                                __builtin_bit_cast(float, p2), __builtin_bit_cast(float, p3));
        *(float4*)&wht[j*128 + ((c ^ (j & 15)) << 3)] = pk;
    }
    hbuf[l] = (_Float16)0.f;
    hbuf[l + 64] = (_Float16)0.f;
    __syncthreads();   // once, after setup

    const int j0 = l, j1 = l + 64;
    const int sw0 = j0 & 15, sw1 = j1 & 15;
    const _Float16* w0r = &wht[j0 * 128];
    const _Float16* w1r = &wht[j1 * 128];

    float apA0 = apre[((size_t)1023*NB + n)*128 + j0];
    float apA1 = apre[((size_t)1023*NB + n)*128 + j1];

    for (int t = 1023; t >= 0; --t) {
        float apN0 = 0.f, apN1 = 0.f;
        if (t >= 1) {
            apN0 = apre[((size_t)(t-1)*NB + n)*128 + j0];
            apN1 = apre[((size_t)(t-1)*NB + n)*128 + j1];
        }

        float a0=0.f, a1=0.f, a2=0.f, a3=0.f;
        float b0=0.f, b1=0.f, b2=0.f, b3=0.f;
        #pragma unroll
        for (int c = 0; c < 16; ++c) {
            float4 hv = *(const float4*)&hbuf[c << 3];              // broadcast
            float4 wv0 = *(const float4*)(w0r + ((c ^ sw0) << 3));
            float4 wv1 = *(const float4*)(w1r + ((c ^ sw1) << 3));
            a0 = dot2(f2h2(hv.x), f2h2(wv0.x), a0);
            a1 = dot2(f2h2(hv.y), f2h2(wv0.y), a1);
            a2 = dot2(f2h2(hv.z), f2h2(wv0.z), a2);
            a3 = dot2(f2h2(hv.w), f2h2(wv0.w), a3);
            b0 = dot2(f2h2(hv.x), f2h2(wv1.x), b0);
            b1 = dot2(f2h2(hv.y), f2h2(wv1.y), b1);
            b2 = dot2(f2h2(hv.z), f2h2(wv1.z), b2);
            b3 = dot2(f2h2(hv.w), f2h2(wv1.w), b3);
        }
        float hc0 = fast_tanh((a0+a1) + (a2+a3) + apA0);
        float hc1 = fast_tanh((b0+b1) + (b2+b3) + apA1);

        hbuf[j0] = (_Float16)hc0;       // compiler orders via lgkmcnt (RAW on hbuf)
        hbuf[j1] = (_Float16)hc1;
        hcell[((size_t)t*NB + n)*128 + j0] = hc0;
        hcell[((size_t)t*NB + n)*128 + j1] = hc1;

        apA0 = apN0; apA1 = apN1;
    }
}

// -------------------------------------------------------------------------
// K3: b = hcell @ wo + bo; alpha = [b[:64], -softplus(b[64:])]
// -------------------------------------------------------------------------
__global__ __launch_bounds__(256) void k_alpha(
    const float* __restrict__ hcell, const float* __restrict__ wo,
    const float* __restrict__ bo, float* __restrict__ alpha)
{
    __shared__ float lhc[8][128];
    const int tid = threadIdx.x;
    const size_t base = (size_t)blockIdx.x * 8 * 128;
    ((float4*)&lhc[0][0])[tid] = ((const float4*)(hcell + base))[tid];
    __syncthreads();

    const int j = tid & 127, rh = tid >> 7;
    float acc[4] = {0,0,0,0};
    for (int i = 0; i < 128; i += 4) {
        float w0 = wo[(i+0)*128 + j];
        float w1v = wo[(i+1)*128 + j];
        float w2v = wo[(i+2)*128 + j];
        float w3 = wo[(i+3)*128 + j];
        #pragma unroll
        for (int q = 0; q < 4; ++q) {
            float4 hv = *(const float4*)&lhc[rh*4+q][i];
            acc[q] += hv.x*w0 + hv.y*w1v + hv.z*w2v + hv.w*w3;
        }
    }
    float bias = bo[j];
    #pragma unroll
    for (int q = 0; q < 4; ++q) {
        float b = acc[q] + bias;
        float val = (j < 64) ? b : -softplus_f(b);
        alpha[base + (size_t)(rh*4+q)*128 + j] = val;
    }
}

// -------------------------------------------------------------------------
// K4: forward posterior scan — SINGLE WAVE per batch, zero barriers.
// Lane l owns output dim d=l (all epilogue math lane-local, no predication).
// L1: lane computes hiddens h = l+64j (j=0..3): dot(m[64], W1T row h).
// L2: lane computes out[l]: dot(hid[256], W2T row l).
// W1T: 256 rows x 128B, chunk' = chunk ^ (h&7); W2T: 64 rows x 512B,
// chunk' = chunk ^ (l&31). m/hid state f16, per-lane b16 writes +
// broadcast b128 reads. LDS total ~64.7 KB.
// -------------------------------------------------------------------------
__global__ __launch_bounds__(64, 1) void k_fwscan(
    const float* __restrict__ alpha, const float* __restrict__ preU,
    const float* __restrict__ dynw1, const float* __restrict__ dynw2,
    const float* __restrict__ dynb2, const float* __restrict__ qraw,
    const float* __restrict__ m0, const float* __restrict__ v0,
    float* __restrict__ out)
{
    const int n = blockIdx.x;
    const int l = threadIdx.x;
    __shared__ __align__(16) _Float16 w1t[256 * 64];   // 32 KB
    __shared__ __align__(16) _Float16 w2t[64 * 256];   // 32 KB
    __shared__ __align__(16) _Float16 mbuf[64];
    __shared__ __align__(16) _Float16 lhid[256];

    // setup W1T[h][i] = dyn_w1[i*256 + h]  (i < 64: m-part only)
    for (int e = l; e < 256 * 8; e += 64) {        // (h, c)
        int h = e & 255, c = e >> 8;
        const float* s = dynw1 + (size_t)(c * 8) * 256 + h;
        h2 p0 = h2{(_Float16)s[0*256], (_Float16)s[1*256]};
        h2 p1 = h2{(_Float16)s[2*256], (_Float16)s[3*256]};
        h2 p2 = h2{(_Float16)s[4*256], (_Float16)s[5*256]};
        h2 p3 = h2{(_Float16)s[6*256], (_Float16)s[7*256]};
        float4 pk = make_float4(__builtin_bit_cast(float, p0), __builtin_bit_cast(float, p1),
                                __builtin_bit_cast(float, p2), __builtin_bit_cast(float, p3));
        *(float4*)&w1t[h*64 + ((c ^ (h & 7)) << 3)] = pk;
    }
    // setup W2T[d][h] = dyn_w2[h*64 + d]
    for (int e = l; e < 64 * 32; e += 64) {        // (d, c)
        int d = e & 63, c = e >> 6;
        const float* s = dynw2 + (size_t)(c * 8) * 64 + d;
        h2 p0 = h2{(_Float16)s[0*64], (_Float16)s[1*64]};
        h2 p1 = h2{(_Float16)s[2*64], (_Float16)s[3*64]};
        h2 p2 = h2{(_Float16)s[4*64], (_Float16)s[5*64]};
        h2 p3 = h2{(_Float16)s[6*64], (_Float16)s[7*64]};
        float4 pk = make_float4(__builtin_bit_cast(float, p0), __builtin_bit_cast(float, p1),
                                __builtin_bit_cast(float, p2), __builtin_bit_cast(float, p3));
        *(float4*)&w2t[d*256 + ((c ^ (d & 31)) << 3)] = pk;
    }
    mbuf[l] = (_Float16)m0[l];
    __syncthreads();   // once, after setup

    const float Qv  = softplus_f(qraw[l]);
    const float b2v = dynb2[l];
    float vreg = v0[l];

    const int sw2 = l & 31;
    const _Float16* w2row = &w2t[l * 256];

    // prefetch ring, distance 1
    float hp0 = preU[(size_t)n*256 + l];
    float hp1 = preU[(size_t)n*256 + l + 64];
    float hp2 = preU[(size_t)n*256 + l + 128];
    float hp3 = preU[(size_t)n*256 + l + 192];
    float al1 = alpha[(size_t)n*128 + l];
    float al2 = alpha[(size_t)n*128 + 64 + l];

    for (int t = 0; t < T_LEN; ++t) {
        float hpN0=0.f, hpN1=0.f, hpN2=0.f, hpN3=0.f, a1N=0.f, a2N=0.f;
        if (t + 1 < T_LEN) {
            size_t pb = ((size_t)(t+1)*NB + n)*256;
            hpN0 = preU[pb + l];
            hpN1 = preU[pb + l + 64];
            hpN2 = preU[pb + l + 128];
            hpN3 = preU[pb + l + 192];
            size_t ab = ((size_t)(t+1)*NB + n)*128;
            a1N = alpha[ab + l];
            a2N = alpha[ab + 64 + l];
        }

        // ---- L1: 4 hiddens per lane (h = l + 64j) ----
        float hpv[4] = {hp0, hp1, hp2, hp3};
        #pragma unroll
        for (int j = 0; j < 4; ++j) {
            const int h = l + 64*j;
            const _Float16* wrow = &w1t[h * 64];
            const int sw = h & 7;
            float a0=0.f, a1=0.f, a2=0.f, a3=0.f;
            #pragma unroll
            for (int c = 0; c < 8; ++c) {
                float4 mv = *(const float4*)&mbuf[c << 3];          // broadcast
                float4 wv = *(const float4*)(wrow + ((c ^ sw) << 3));
                a0 = dot2(f2h2(mv.x), f2h2(wv.x), a0);
                a1 = dot2(f2h2(mv.y), f2h2(wv.y), a1);
                a2 = dot2(f2h2(mv.z), f2h2(wv.z), a2);
                a3 = dot2(f2h2(mv.w), f2h2(wv.w), a3);
            }
            lhid[h] = (_Float16)fast_tanh(hpv[j] + (a0+a1) + (a2+a3));
        }

        // ---- L2: one output per lane (d = l) ----
        float b0=0.f, b1=0.f, b2p=0.f, b3=0.f;
        #pragma unroll
        for (int c = 0; c < 32; ++c) {
            float4 hv = *(const float4*)&lhid[c << 3];              // broadcast
            float4 wv = *(const float4*)(w2row + ((c ^ sw2) << 3));
            b0  = dot2(f2h2(hv.x), f2h2(wv.x), b0);
            b1  = dot2(f2h2(hv.y), f2h2(wv.y), b1);
            b2p = dot2(f2h2(hv.z), f2h2(wv.z), b2p);
            b3  = dot2(f2h2(hv.w), f2h2(wv.w), b3);
        }
        float m_p = (b0+b1) + (b2p+b3) + b2v;
        float v_p = vreg + Qv;
        float rvp = __builtin_amdgcn_rcpf(v_p);
        float e1 = m_p * rvp + al1;
        float e2 = al2 - 0.5f * rvp;
        float v_s = -0.5f * __builtin_amdgcn_rcpf(e2);
        float m_s = v_s * e1;
        vreg = v_s;
        mbuf[l] = (_Float16)m_s;        // ordered vs next-step reads by lgkmcnt

        size_t ob = ((size_t)n * T_LEN + t) * 256;
        out[ob + l]       = m_s;
        out[ob + 64 + l]  = v_s;
        out[ob + 128 + l] = m_p;
        out[ob + 192 + l] = v_p;

        hp0 = hpN0; hp1 = hpN1; hp2 = hpN2; hp3 = hpN3;
        al1 = a1N;  al2 = a2N;
    }
}

// -------------------------------------------------------------------------
extern "C" void kernel_launch(void* const* d_in, const int* in_sizes, int n_in,
                              void* d_out, int out_size, void* d_ws, size_t ws_size,
                              hipStream_t stream) {
    const float* y      = (const float*)d_in[1];
    const float* u      = (const float*)d_in[2];
    const float* enc_w1 = (const float*)d_in[3];
    const float* enc_b1 = (const float*)d_in[4];
    const float* enc_w2 = (const float*)d_in[5];
    const float* enc_b2 = (const float*)d_in[6];
    const float* bw_wa  = (const float*)d_in[7];
    const float* bw_wh  = (const float*)d_in[8];
    const float* bw_b   = (const float*)d_in[9];
    const float* bw_wo  = (const float*)d_in[10];
    const float* bw_bo  = (const float*)d_in[11];
    const float* dyn_w1 = (const float*)d_in[12];
    const float* dyn_b1 = (const float*)d_in[13];
    const float* dyn_w2 = (const float*)d_in[14];
    const float* dyn_b2 = (const float*)d_in[15];
    const float* q_raw  = (const float*)d_in[16];
    const float* m0     = (const float*)d_in[17];
    const float* v0     = (const float*)d_in[18];
    float* out = (float*)d_out;

    float* ws = (float*)d_ws;
    float* apre  = ws;                  // [T*NB][128]
    float* hcell = ws + 4194304;        // [T*NB][128]
    float* alpha = ws;                  // aliases apre (apre dead after K2)
    float* preU  = ws + 2 * 4194304;    // [T*NB][256]

    k_encoder<<<4096, 256, 0, stream>>>(y, u, enc_w1, enc_b1, enc_w2, enc_b2,
                                        bw_wa, bw_b, dyn_w1, dyn_b1, apre, preU);
    k_bwscan<<<NB, 64, 0, stream>>>(apre, bw_wh, hcell);
    k_alpha<<<4096, 256, 0, stream>>>(hcell, bw_wo, bw_bo, alpha);
    k_fwscan<<<NB, 64, 0, stream>>>(alpha, preU, dyn_w1, dyn_w2, dyn_b2,
                                    q_raw, m0, v0, out);
}

// Round 8
// 1985.129 us; speedup vs baseline: 1.1130x; 1.1130x over previous
//
#include <hip/hip_runtime.h>
#include <math.h>

// XFADS: N=32, T=1024, D_OBS=128, D_Z=64, D_U=8, H_ENC=256, H_BW=128, H_DYN=256, D_A=128
#define T_LEN 1024
#define NB 32

typedef _Float16 f16x8 __attribute__((ext_vector_type(8)));
typedef float f32x4 __attribute__((ext_vector_type(4)));

__device__ __forceinline__ float softplus_f(float x) {
    return fmaxf(x, 0.f) + log1pf(expf(-fabsf(x)));
}

__device__ __forceinline__ float fast_tanh(float x) {
    float e = __builtin_amdgcn_exp2f(x * 2.88539008177792681472f);
    float r = __builtin_amdgcn_rcpf(1.f + e);
    return 1.f - 2.f * r;
}

// raw barrier: drain LDS ops only; global prefetches stay in flight (T4 pattern)
__device__ __forceinline__ void bar_sync() {
    asm volatile("s_waitcnt lgkmcnt(0)" ::: "memory");
    __builtin_amdgcn_s_barrier();
    asm volatile("" ::: "memory");
}

// -------------------------------------------------------------------------
// K1: encoder  h = tanh(y@W1+b1); a = h@W2+b2;
//     apre[t][n][:] = a@bw_wa + bw_b
//     preU[t][n][:] = u@dyn_w1[64:72] + dyn_b1
// -------------------------------------------------------------------------
__global__ __launch_bounds__(256) void k_encoder(
    const float* __restrict__ y, const float* __restrict__ u,
    const float* __restrict__ w1, const float* __restrict__ b1,
    const float* __restrict__ w2, const float* __restrict__ b2,
    const float* __restrict__ wa, const float* __restrict__ bb,
    const float* __restrict__ dynw1, const float* __restrict__ dynb1,
    float* __restrict__ apre, float* __restrict__ preU)
{
    __shared__ float ly[8][128];
    __shared__ float lh[8][256];
    __shared__ float la[8][128];
    __shared__ float lu[8][8];
    const int tid = threadIdx.x;
    const int row0 = blockIdx.x * 8;

    ((float4*)&ly[0][0])[tid] = ((const float4*)(y + (size_t)row0 * 128))[tid];
    if (tid < 16)
        ((float4*)&lu[0][0])[tid] = ((const float4*)(u + (size_t)row0 * 8))[tid];
    __syncthreads();

    {
        float acc[8] = {0,0,0,0,0,0,0,0};
        for (int i = 0; i < 128; i += 4) {
            float w0 = w1[(i+0)*256 + tid];
            float w1v = w1[(i+1)*256 + tid];
            float w2v = w1[(i+2)*256 + tid];
            float w3 = w1[(i+3)*256 + tid];
            #pragma unroll
            for (int r = 0; r < 8; ++r) {
                float4 yv = *(const float4*)&ly[r][i];
                acc[r] += yv.x*w0 + yv.y*w1v + yv.z*w2v + yv.w*w3;
            }
        }
        float bias = b1[tid];
        #pragma unroll
        for (int r = 0; r < 8; ++r) lh[r][tid] = fast_tanh(acc[r] + bias);
    }
    __syncthreads();

    {
        const int d = tid & 127, rh = tid >> 7;
        float acc[4] = {0,0,0,0};
        for (int i = 0; i < 256; i += 4) {
            float w0 = w2[(i+0)*128 + d];
            float w1v = w2[(i+1)*128 + d];
            float w2v = w2[(i+2)*128 + d];
            float w3 = w2[(i+3)*128 + d];
            #pragma unroll
            for (int q = 0; q < 4; ++q) {
                float4 hv = *(const float4*)&lh[rh*4+q][i];
                acc[q] += hv.x*w0 + hv.y*w1v + hv.z*w2v + hv.w*w3;
            }
        }
        float bias = b2[d];
        #pragma unroll
        for (int q = 0; q < 4; ++q) la[rh*4+q][d] = acc[q] + bias;
    }
    __syncthreads();

    {
        const int j = tid & 127, rh = tid >> 7;
        float acc[4] = {0,0,0,0};
        for (int i = 0; i < 128; i += 4) {
            float w0 = wa[(i+0)*128 + j];
            float w1v = wa[(i+1)*128 + j];
            float w2v = wa[(i+2)*128 + j];
            float w3 = wa[(i+3)*128 + j];
            #pragma unroll
            for (int q = 0; q < 4; ++q) {
                float4 av = *(const float4*)&la[rh*4+q][i];
                acc[q] += av.x*w0 + av.y*w1v + av.z*w2v + av.w*w3;
            }
        }
        float bias = bb[j];
        #pragma unroll
        for (int q = 0; q < 4; ++q) {
            int rn = row0 + rh*4 + q;
            int n = rn >> 10, t = rn & 1023;
            apre[((size_t)t*NB + n)*128 + j] = acc[q] + bias;
        }
    }

    {
        float wu[8];
        #pragma unroll
        for (int c = 0; c < 8; ++c) wu[c] = dynw1[(64 + c)*256 + tid];
        float bias = dynb1[tid];
        #pragma unroll
        for (int r = 0; r < 8; ++r) {
            float acc = bias;
            #pragma unroll
            for (int c = 0; c < 8; ++c) acc += lu[r][c] * wu[c];
            int rn = row0 + r;
            int n = rn >> 10, t = rn & 1023;
            preU[((size_t)t*NB + n)*256 + tid] = acc;
        }
    }
}

// -------------------------------------------------------------------------
// K2: backward RNN scan via MFMA. 2 blocks x 16 batches, 4 waves (256 thr).
// Per step: hcell[16x128] = tanh(apre + H[16x128] @ Wh[128x128]).
// A-frag: lane holds H[l&15][kt*32 + (l>>4)*8 + i] (b128 from swizzled LDS).
// B-frags (Wh) in REGISTERS, loaded once: wave w owns n-tiles {2w,2w+1}.
// C/D: row(batch)=(l>>4)*4+reg, col=l&15 (HW-verified). H double-buffered ->
// ONE barrier/step. apre prefetch ring distance 1.
// -------------------------------------------------------------------------
__global__ __launch_bounds__(256, 1) void k_bwscan(
    const float* __restrict__ apre, const float* __restrict__ wh,
    float* __restrict__ hcell)
{
    const int nb = blockIdx.x * 16;
    const int tid = threadIdx.x;
    const int w = tid >> 6, l = tid & 63;
    const int g = l >> 4, c = l & 15;
    __shared__ __align__(16) _Float16 Hld[2][16 * 128];

    // B frags: Bf[kt][nt], elem i = Wh[kt*32+g*8+i][(2w+nt)*16+c]
    f16x8 Bf[4][2];
    #pragma unroll
    for (int kt = 0; kt < 4; ++kt)
        #pragma unroll
        for (int nt = 0; nt < 2; ++nt) {
            f16x8 v;
            #pragma unroll
            for (int i = 0; i < 8; ++i)
                v[i] = (_Float16)wh[(size_t)(kt*32 + g*8 + i)*128 + (2*w + nt)*16 + c];
            Bf[kt][nt] = v;
        }

    for (int e = tid; e < 16 * 128; e += 256) Hld[0][e] = (_Float16)0.f;
    __syncthreads();

    float ap[2][4];
    #pragma unroll
    for (int nt = 0; nt < 2; ++nt)
        #pragma unroll
        for (int r = 0; r < 4; ++r)
            ap[nt][r] = apre[((size_t)1023*NB + nb + g*4 + r)*128 + (2*w + nt)*16 + c];

    int cur = 0;
    for (int t = 1023; t >= 0; --t) {
        float apN[2][4];
        #pragma unroll
        for (int nt = 0; nt < 2; ++nt)
            #pragma unroll
            for (int r = 0; r < 4; ++r)
                apN[nt][r] = (t > 0)
                    ? apre[((size_t)(t-1)*NB + nb + g*4 + r)*128 + (2*w + nt)*16 + c]
                    : 0.f;

        // A-frags from H_lds (swizzled chunks -> ~2-way banks = free)
        f16x8 a0 = *(const f16x8*)&Hld[cur][c*128 + (((0*4 + g) ^ (c & 7)) << 3)];
        f16x8 a1 = *(const f16x8*)&Hld[cur][c*128 + (((1*4 + g) ^ (c & 7)) << 3)];
        f16x8 a2 = *(const f16x8*)&Hld[cur][c*128 + (((2*4 + g) ^ (c & 7)) << 3)];
        f16x8 a3 = *(const f16x8*)&Hld[cur][c*128 + (((3*4 + g) ^ (c & 7)) << 3)];

        #pragma unroll
        for (int nt = 0; nt < 2; ++nt) {
            f32x4 acc = {0.f, 0.f, 0.f, 0.f};
            acc = __builtin_amdgcn_mfma_f32_16x16x32_f16(a0, Bf[0][nt], acc, 0, 0, 0);
            acc = __builtin_amdgcn_mfma_f32_16x16x32_f16(a1, Bf[1][nt], acc, 0, 0, 0);
            acc = __builtin_amdgcn_mfma_f32_16x16x32_f16(a2, Bf[2][nt], acc, 0, 0, 0);
            acc = __builtin_amdgcn_mfma_f32_16x16x32_f16(a3, Bf[3][nt], acc, 0, 0, 0);
            #pragma unroll
            for (int r = 0; r < 4; ++r) {
                int b = g*4 + r;
                int j = (2*w + nt)*16 + c;
                float hc = fast_tanh(acc[r] + ap[nt][r]);
                Hld[cur ^ 1][b*128 + (((j >> 3) ^ (b & 7)) << 3) + (j & 7)] = (_Float16)hc;
                hcell[((size_t)t*NB + nb + b)*128 + j] = hc;
            }
        }
        bar_sync();
        cur ^= 1;
        #pragma unroll
        for (int nt = 0; nt < 2; ++nt)
            #pragma unroll
            for (int r = 0; r < 4; ++r) ap[nt][r] = apN[nt][r];
    }
}

// -------------------------------------------------------------------------
// K3: b = hcell @ wo + bo; alpha = [b[:64], -softplus(b[64:])]
// -------------------------------------------------------------------------
__global__ __launch_bounds__(256) void k_alpha(
    const float* __restrict__ hcell, const float* __restrict__ wo,
    const float* __restrict__ bo, float* __restrict__ alpha)
{
    __shared__ float lhc[8][128];
    const int tid = threadIdx.x;
    const size_t base = (size_t)blockIdx.x * 8 * 128;
    ((float4*)&lhc[0][0])[tid] = ((const float4*)(hcell + base))[tid];
    __syncthreads();

    const int j = tid & 127, rh = tid >> 7;
    float acc[4] = {0,0,0,0};
    for (int i = 0; i < 128; i += 4) {
        float w0 = wo[(i+0)*128 + j];
        float w1v = wo[(i+1)*128 + j];
        float w2v = wo[(i+2)*128 + j];
        float w3 = wo[(i+3)*128 + j];
        #pragma unroll
        for (int q = 0; q < 4; ++q) {
            float4 hv = *(const float4*)&lhc[rh*4+q][i];
            acc[q] += hv.x*w0 + hv.y*w1v + hv.z*w2v + hv.w*w3;
        }
    }
    float bias = bo[j];
    #pragma unroll
    for (int q = 0; q < 4; ++q) {
        float b = acc[q] + bias;
        float val = (j < 64) ? b : -softplus_f(b);
        alpha[base + (size_t)(rh*4+q)*128 + j] = val;
    }
}

// -------------------------------------------------------------------------
// K4: forward posterior scan via MFMA. 2 blocks x 16 batches, 4 waves.
// G1: HID[16x256] = tanh(preU + M[16x64] @ W1m[64x256]) — wave w owns
//     n-tiles {4w..4w+3}; B1 frags in regs (8 x f16x8).
// G2: PRED[16x64] = HID @ W2[256x64] — wave w owns n-tile w; B2 in regs.
// Posterior epilogue per lane: 4 (batch,d) pairs; v kept in registers.
// M/HID single-buffered (2 barriers/step separate all RW phases).
// -------------------------------------------------------------------------
__global__ __launch_bounds__(256, 1) void k_fwscan(
    const float* __restrict__ alpha, const float* __restrict__ preU,
    const float* __restrict__ dynw1, const float* __restrict__ dynw2,
    const float* __restrict__ dynb2, const float* __restrict__ qraw,
    const float* __restrict__ m0, const float* __restrict__ v0,
    float* __restrict__ out)
{
    const int nb = blockIdx.x * 16;
    const int tid = threadIdx.x;
    const int w = tid >> 6, l = tid & 63;
    const int g = l >> 4, c = l & 15;
    __shared__ __align__(16) _Float16 Mld[16 * 64];
    __shared__ __align__(16) _Float16 Hid[16 * 256];

    // B1 frags: [kt][nt], elem i = W1[kt*32+g*8+i][(4w+nt)*16+c]
    f16x8 B1[2][4];
    #pragma unroll
    for (int kt = 0; kt < 2; ++kt)
        #pragma unroll
        for (int nt = 0; nt < 4; ++nt) {
            f16x8 v;
            #pragma unroll
            for (int i = 0; i < 8; ++i)
                v[i] = (_Float16)dynw1[(size_t)(kt*32 + g*8 + i)*256 + (4*w + nt)*16 + c];
            B1[kt][nt] = v;
        }
    // B2 frags: [kt], elem i = W2[kt*32+g*8+i][w*16+c]
    f16x8 B2[8];
    #pragma unroll
    for (int kt = 0; kt < 8; ++kt) {
        f16x8 v;
        #pragma unroll
        for (int i = 0; i < 8; ++i)
            v[i] = (_Float16)dynw2[(size_t)(kt*32 + g*8 + i)*64 + w*16 + c];
        B2[kt] = v;
    }

    const int d = w*16 + c;
    const float Qv  = softplus_f(qraw[d]);
    const float b2v = dynb2[d];
    float vreg[4];
    #pragma unroll
    for (int r = 0; r < 4; ++r) vreg[r] = v0[d];

    for (int e = tid; e < 1024; e += 256) {
        int b = e >> 6, dd = e & 63;
        Mld[b*64 + (((dd >> 3) ^ (b & 7)) << 3) + (dd & 7)] = (_Float16)m0[dd];
    }
    __syncthreads();

    float hp[4][4], al1[4], al2[4];
    #pragma unroll
    for (int nt = 0; nt < 4; ++nt)
        #pragma unroll
        for (int r = 0; r < 4; ++r)
            hp[nt][r] = preU[((size_t)nb + g*4 + r)*256 + (4*w + nt)*16 + c];
    #pragma unroll
    for (int r = 0; r < 4; ++r) {
        al1[r] = alpha[((size_t)nb + g*4 + r)*128 + d];
        al2[r] = alpha[((size_t)nb + g*4 + r)*128 + 64 + d];
    }

    for (int t = 0; t < T_LEN; ++t) {
        bar_sync();   // M ready (prev ep2 writes drained+synced)

        float hpN[4][4], al1N[4], al2N[4];
        if (t + 1 < T_LEN) {
            #pragma unroll
            for (int nt = 0; nt < 4; ++nt)
                #pragma unroll
                for (int r = 0; r < 4; ++r)
                    hpN[nt][r] = preU[((size_t)(t+1)*NB + nb + g*4 + r)*256 + (4*w + nt)*16 + c];
            #pragma unroll
            for (int r = 0; r < 4; ++r) {
                al1N[r] = alpha[((size_t)(t+1)*NB + nb + g*4 + r)*128 + d];
                al2N[r] = alpha[((size_t)(t+1)*NB + nb + g*4 + r)*128 + 64 + d];
            }
        } else {
            #pragma unroll
            for (int nt = 0; nt < 4; ++nt)
                #pragma unroll
                for (int r = 0; r < 4; ++r) hpN[nt][r] = 0.f;
            #pragma unroll
            for (int r = 0; r < 4; ++r) { al1N[r] = 0.f; al2N[r] = 0.f; }
        }

        // G1: A-frags from M_lds
        f16x8 a1_0 = *(const f16x8*)&Mld[c*64 + (((0*4 + g) ^ (c & 7)) << 3)];
        f16x8 a1_1 = *(const f16x8*)&Mld[c*64 + (((1*4 + g) ^ (c & 7)) << 3)];
        #pragma unroll
        for (int nt = 0; nt < 4; ++nt) {
            f32x4 acc = {0.f, 0.f, 0.f, 0.f};
            acc = __builtin_amdgcn_mfma_f32_16x16x32_f16(a1_0, B1[0][nt], acc, 0, 0, 0);
            acc = __builtin_amdgcn_mfma_f32_16x16x32_f16(a1_1, B1[1][nt], acc, 0, 0, 0);
            #pragma unroll
            for (int r = 0; r < 4; ++r) {
                int b = g*4 + r;
                int h = (4*w + nt)*16 + c;
                float hv = fast_tanh(hp[nt][r] + acc[r]);
                Hid[b*256 + (((h >> 3) ^ (b & 7)) << 3) + (h & 7)] = (_Float16)hv;
            }
        }
        bar_sync();   // HID ready

        // G2: 8-k chain
        f32x4 acc2 = {0.f, 0.f, 0.f, 0.f};
        #pragma unroll
        for (int kt = 0; kt < 8; ++kt) {
            f16x8 a2 = *(const f16x8*)&Hid[c*256 + (((kt*4 + g) ^ (c & 7)) << 3)];
            acc2 = __builtin_amdgcn_mfma_f32_16x16x32_f16(a2, B2[kt], acc2, 0, 0, 0);
        }
        // ep2: posterior update, M write, out stores
        #pragma unroll
        for (int r = 0; r < 4; ++r) {
            int b = g*4 + r;
            float m_p = acc2[r] + b2v;
            float v_p = vreg[r] + Qv;
            float rvp = __builtin_amdgcn_rcpf(v_p);
            float e1 = m_p * rvp + al1[r];
            float e2 = al2[r] - 0.5f * rvp;
            float v_s = -0.5f * __builtin_amdgcn_rcpf(e2);
            float m_s = v_s * e1;
            vreg[r] = v_s;
            Mld[b*64 + (((d >> 3) ^ (b & 7)) << 3) + (d & 7)] = (_Float16)m_s;
            size_t ob = ((size_t)(nb + b)*T_LEN + t)*256;
            out[ob + d]       = m_s;
            out[ob + 64 + d]  = v_s;
            out[ob + 128 + d] = m_p;
            out[ob + 192 + d] = v_p;
        }

        #pragma unroll
        for (int nt = 0; nt < 4; ++nt)
            #pragma unroll
            for (int r = 0; r < 4; ++r) hp[nt][r] = hpN[nt][r];
        #pragma unroll
        for (int r = 0; r < 4; ++r) { al1[r] = al1N[r]; al2[r] = al2N[r]; }
    }
}

// -------------------------------------------------------------------------
extern "C" void kernel_launch(void* const* d_in, const int* in_sizes, int n_in,
                              void* d_out, int out_size, void* d_ws, size_t ws_size,
                              hipStream_t stream) {
    const float* y      = (const float*)d_in[1];
    const float* u      = (const float*)d_in[2];
    const float* enc_w1 = (const float*)d_in[3];
    const float* enc_b1 = (const float*)d_in[4];
    const float* enc_w2 = (const float*)d_in[5];
    const float* enc_b2 = (const float*)d_in[6];
    const float* bw_wa  = (const float*)d_in[7];
    const float* bw_wh  = (const float*)d_in[8];
    const float* bw_b   = (const float*)d_in[9];
    const float* bw_wo  = (const float*)d_in[10];
    const float* bw_bo  = (const float*)d_in[11];
    const float* dyn_w1 = (const float*)d_in[12];
    const float* dyn_b1 = (const float*)d_in[13];
    const float* dyn_w2 = (const float*)d_in[14];
    const float* dyn_b2 = (const float*)d_in[15];
    const float* q_raw  = (const float*)d_in[16];
    const float* m0     = (const float*)d_in[17];
    const float* v0     = (const float*)d_in[18];
    float* out = (float*)d_out;

    float* ws = (float*)d_ws;
    float* apre  = ws;                  // [T*NB][128]
    float* hcell = ws + 4194304;        // [T*NB][128]
    float* alpha = ws;                  // aliases apre (apre dead after K2)
    float* preU  = ws + 2 * 4194304;    // [T*NB][256]

    k_encoder<<<4096, 256, 0, stream>>>(y, u, enc_w1, enc_b1, enc_w2, enc_b2,
                                        bw_wa, bw_b, dyn_w1, dyn_b1, apre, preU);
    k_bwscan<<<2, 256, 0, stream>>>(apre, bw_wh, hcell);
    k_alpha<<<4096, 256, 0, stream>>>(hcell, bw_wo, bw_bo, alpha);
    k_fwscan<<<2, 256, 0, stream>>>(alpha, preU, dyn_w1, dyn_w2, dyn_b2,
                                    q_raw, m0, v0, out);
}